// Round 10
// baseline (116.911 us; speedup 1.0000x reference)
//
#include <hip/hip_runtime.h>
#include <hip/hip_bf16.h>

#define NL    64
#define DIN   512
#define DOUT  512
#define BATCH 1024

#define BM 256
#define BN 256
#define BK 64
#define NT (DIN / BK)   // 8 K-tiles

typedef short short8 __attribute__((ext_vector_type(8)));
typedef float f32x4  __attribute__((ext_vector_type(4)));

__device__ __forceinline__ unsigned int pk2(float a, float b) {
    // v_cvt_pk_bf16_f32 (RNE)
    __hip_bfloat162 h = __float22bfloat162_rn(make_float2(a, b));
    unsigned int r;
    __builtin_memcpy(&r, &h, 4);
    return r;
}

__global__ __launch_bounds__(512, 2) void nlinear_kernel(
        const float* __restrict__ x, const float* __restrict__ w,
        const float* __restrict__ bias, float* __restrict__ out) {
    // Dynamic LDS 128 KB: A[2][256][64] bf16 + B[2][256][64] bf16.
    // 128B rows (bank-aligned); 16B-slot XOR swizzle: slot ^= (row & 7).
    extern __shared__ unsigned short lds[];
    unsigned short* const Abuf = lds;                  // 2 x 32 KB
    unsigned short* const Bbuf = lds + 2 * BM * BK;    // 2 x 32 KB

    const int tid = threadIdx.x;
    const int bid = blockIdx.x;
    // XCD swizzle: 512 blocks = 8 XCDs x 64; each XCD owns 8 whole layers.
    const int nb    = (bid & 7) * 64 + (bid >> 3);
    const int layer = nb >> 3;
    const int t8    = nb & 7;
    const int bm0   = (t8 & 3) * BM;
    const int bn0   = (t8 >> 2) * BN;

    const int wid  = tid >> 6;
    const int lane = tid & 63;
    const int wr   = wid >> 2, wc = wid & 3;   // 2M x 4N waves, 128x64 each
    const int lrow = lane & 15;
    const int lkb  = lane >> 4;                // k-octet 0..3

    // A-stage: ar = tid>>3 (0..63), rows ar+64j; ac = tid&7 (8 fp32 chunk)
    const int ar = tid >> 3;
    const int ac = tid & 7;
    // B-stage: kq = tid&15 (4 k-rows kq*4+ki); cg = tid>>4 (8 cols cg*8+j)
    const int kq = tid & 15;
    const int cg = tid >> 4;

    const size_t XS = (size_t)NL * DIN;
    const float* xb = x + (size_t)bm0 * XS + (size_t)layer * DIN;
    const float* wb = w + (size_t)layer * DIN * DOUT + bn0;
    const float* aptr = xb + (size_t)ar * XS + ac * 8;
    const float* bptr = wb + (size_t)(kq * 4) * DOUT + cg * 8;

    f32x4 acc[8][4];
#pragma unroll
    for (int i = 0; i < 8; ++i)
#pragma unroll
        for (int j = 0; j < 4; ++j) acc[i][j] = (f32x4){0.f, 0.f, 0.f, 0.f};

    f32x4 avr[4][2];    // A staging regs: [j: row ar+64j][half]
    f32x4 bvr[4][2];    // B staging regs: [ki][half]

    auto issueA = [&](int t) {
#pragma unroll
        for (int j = 0; j < 4; ++j) {
            const float* p = aptr + (size_t)(64 * j) * XS + t * BK;
            avr[j][0] = *reinterpret_cast<const f32x4*>(p);
            avr[j][1] = *reinterpret_cast<const f32x4*>(p + 4);
        }
    };
    auto issueB = [&](int t) {
#pragma unroll
        for (int ki = 0; ki < 4; ++ki) {
            const float* p = bptr + (size_t)(t * BK + ki) * DOUT;
            bvr[ki][0] = *reinterpret_cast<const f32x4*>(p);
            bvr[ki][1] = *reinterpret_cast<const f32x4*>(p + 4);
        }
    };
    // A cvt+write, part p (rows j=2p, 2p+1): 2x ds_write_b128
    auto cvtwriteA = [&](int db, int p) {
        unsigned short* dst = Abuf + db * (BM * BK);
#pragma unroll
        for (int jj = 0; jj < 2; ++jj) {
            const int j = 2 * p + jj;
            const int r = ar + 64 * j;
            uint4 wv;
            wv.x = pk2(avr[j][0][0], avr[j][0][1]);
            wv.y = pk2(avr[j][0][2], avr[j][0][3]);
            wv.z = pk2(avr[j][1][0], avr[j][1][1]);
            wv.w = pk2(avr[j][1][2], avr[j][1][3]);
            *reinterpret_cast<uint4*>(&dst[r * BK + ((ac ^ (r & 7)) << 3)]) = wv;
        }
    };
    // B transpose cvt+write, part p (cols j=4p..4p+3): 4x ds_write_b64
    auto cvtwriteB = [&](int db, int p) {
        unsigned short* dst = Bbuf + db * (BN * BK);
#pragma unroll
        for (int jj = 0; jj < 4; ++jj) {
            const int j = 4 * p + jj;
            const int c = cg * 8 + j;
            const int h = j >> 2, e = j & 3;
            uint2 wv;
            wv.x = pk2(bvr[0][h][e], bvr[1][h][e]);
            wv.y = pk2(bvr[2][h][e], bvr[3][h][e]);
            const int off = c * BK + (((kq >> 1) ^ (c & 7)) << 3) + ((kq & 1) << 2);
            *reinterpret_cast<uint2*>(&dst[off]) = wv;
        }
    };

    auto fragA = [&](int db, int kh, int mh, short8* af) {
        const unsigned short* src = Abuf + db * (BM * BK);
#pragma unroll
        for (int mi = 0; mi < 4; ++mi) {
            const int row = wr * 128 + mh * 64 + mi * 16 + lrow;
            const int s = kh * 4 + lkb;
            af[mi] = *reinterpret_cast<const short8*>(
                &src[row * BK + ((s ^ (row & 7)) << 3)]);
        }
    };
    auto fragB = [&](int db, int kh, short8* bf) {
        const unsigned short* src = Bbuf + db * (BN * BK);
#pragma unroll
        for (int ni = 0; ni < 4; ++ni) {
            const int col = wc * 64 + ni * 16 + lrow;
            const int s = kh * 4 + lkb;
            bf[ni] = *reinterpret_cast<const short8*>(
                &src[col * BK + ((s ^ (col & 7)) << 3)]);
        }
    };

#define PHASE_SYNC_PRE() do { \
        __builtin_amdgcn_s_barrier(); \
        asm volatile("s_waitcnt lgkmcnt(0)" ::: "memory"); \
        __builtin_amdgcn_sched_barrier(0); } while (0)
#define PHASE_SYNC_POST() do { \
        __builtin_amdgcn_sched_barrier(0); \
        __builtin_amdgcn_s_barrier(); } while (0)

#define MFMA16(MH, AF, BF) do { \
        __builtin_amdgcn_s_setprio(1); \
        _Pragma("unroll") \
        for (int mi = 0; mi < 4; ++mi) \
        _Pragma("unroll") \
            for (int ni = 0; ni < 4; ++ni) \
                acc[(MH) * 4 + mi][ni] = __builtin_amdgcn_mfma_f32_16x16x32_bf16( \
                    AF[mi], BF[ni], acc[(MH) * 4 + mi][ni], 0, 0, 0); \
        __builtin_amdgcn_s_setprio(0); } while (0)

    // ---- prologue: tile0 -> buf0; tile1 loads in flight ----
    issueA(0); issueB(0);
    cvtwriteA(0, 0); cvtwriteA(0, 1);
    cvtwriteB(0, 0); cvtwriteB(0, 1);
    issueA(1); issueB(1);
    asm volatile("s_waitcnt lgkmcnt(0)" ::: "memory");
    __builtin_amdgcn_sched_barrier(0);
    __builtin_amdgcn_s_barrier();

    // ---- main loop: 4 phases per K-tile, 2 barriers per phase ----
#pragma unroll 1
    for (int t = 0; t < NT; ++t) {
        const int cur = t & 1, oth = cur ^ 1;
        short8 af[4], bf[4];

        // Phase 0: (kh0, mh0) + stage part 0 of tile t+1
        fragB(cur, 0, bf);
        fragA(cur, 0, 0, af);
        if (t < NT - 1) { cvtwriteA(oth, 0); cvtwriteB(oth, 0); }
        PHASE_SYNC_PRE();
        MFMA16(0, af, bf);
        PHASE_SYNC_POST();

        // Phase 1: (kh0, mh1) + stage part 1 of tile t+1
        fragA(cur, 0, 1, af);
        if (t < NT - 1) { cvtwriteA(oth, 1); cvtwriteB(oth, 1); }
        PHASE_SYNC_PRE();
        MFMA16(1, af, bf);
        PHASE_SYNC_POST();

        // Phase 2: (kh1, mh0) + issue A loads for tile t+2
        fragB(cur, 1, bf);
        fragA(cur, 1, 0, af);
        if (t < NT - 2) issueA(t + 2);
        PHASE_SYNC_PRE();
        MFMA16(0, af, bf);
        PHASE_SYNC_POST();

        // Phase 3: (kh1, mh1) + issue B loads for tile t+2
        fragA(cur, 1, 1, af);
        if (t < NT - 2) issueB(t + 2);
        PHASE_SYNC_PRE();
        MFMA16(1, af, bf);
        PHASE_SYNC_POST();
    }

    // ---- epilogue: + bias, fp32 store ----
    const float* bb = bias + (size_t)layer * DOUT + bn0;
    float* ob = out + (size_t)bm0 * (NL * DOUT) + (size_t)layer * DOUT + bn0;
#pragma unroll
    for (int m8 = 0; m8 < 8; ++m8) {
#pragma unroll
        for (int ni = 0; ni < 4; ++ni) {
            const int col = wc * 64 + ni * 16 + lrow;
            const float bval = bb[col];
#pragma unroll
            for (int r = 0; r < 4; ++r) {
                const int row = wr * 128 + (m8 >> 2) * 64 + (m8 & 3) * 16
                              + lkb * 4 + r;
                ob[(size_t)row * (NL * DOUT) + col] = acc[m8][ni][r] + bval;
            }
        }
    }
#undef PHASE_SYNC_PRE
#undef PHASE_SYNC_POST
#undef MFMA16
}

extern "C" void kernel_launch(void* const* d_in, const int* in_sizes, int n_in,
                              void* d_out, int out_size, void* d_ws, size_t ws_size,
                              hipStream_t stream) {
    const float* x  = (const float*)d_in[0];
    const float* w  = (const float*)d_in[1];
    const float* b  = (const float*)d_in[2];
    float* out      = (float*)d_out;

    static const size_t lds_bytes = 2 * (size_t)(BM * BK + BN * BK) * 2; // 131072
    hipFuncSetAttribute((const void*)nlinear_kernel,
                        hipFuncAttributeMaxDynamicSharedMemorySize,
                        (int)lds_bytes);

    dim3 grid(NL * (BATCH / BM) * (DOUT / BN));   // 64 * 4 * 2 = 512
    dim3 block(512);
    hipLaunchKernelGGL(nlinear_kernel, grid, block, lds_bytes, stream,
                       x, w, b, out);
}

// Round 11
// 93.110 us; speedup vs baseline: 1.2556x; 1.2556x over previous
//
#include <hip/hip_runtime.h>
#include <hip/hip_bf16.h>

#define NL    64
#define DIN   512
#define DOUT  512
#define BATCH 1024

#define BM 256
#define BN 256
#define BK 32
#define NK (DIN / BK)   // 16
#define LDSS 40         // padded row stride in shorts (80 B)

typedef short short8 __attribute__((ext_vector_type(8)));
typedef float f32x4  __attribute__((ext_vector_type(4)));

__device__ __forceinline__ unsigned int pk2(float a, float b) {
    // v_cvt_pk_bf16_f32 (RNE)
    __hip_bfloat162 h = __float22bfloat162_rn(make_float2(a, b));
    unsigned int r;
    __builtin_memcpy(&r, &h, 4);
    return r;
}

__global__ __launch_bounds__(512, 2) void nlinear_kernel(
        const float* __restrict__ x, const float* __restrict__ w,
        const float* __restrict__ bias, float* __restrict__ out) {
    // Double-buffered bf16 tiles [row][k], stride 40 shorts (80 B).
    // A: plain pad layout (writes/reads verified <=2-way).
    // B: 8B-slot XOR swizzle: quad q of col c at slot q ^ ((c>>2)&7).
    __shared__ unsigned short As[2][BM * LDSS];   // 2 x 20 KB
    __shared__ unsigned short Bs[2][BN * LDSS];   // 2 x 20 KB

    const int tid = threadIdx.x;
    const int bid = blockIdx.x;
    // XCD swizzle: 512 blocks = 8 XCDs x 64; each XCD owns 8 whole layers.
    const int nb    = (bid & 7) * 64 + (bid >> 3);
    const int layer = nb >> 3;
    const int t8    = nb & 7;
    const int bm0   = (t8 & 3) * BM;
    const int bn0   = (t8 >> 2) * BN;

    const int wid  = tid >> 6;
    const int lane = tid & 63;
    const int wr   = wid >> 2, wc = wid & 3;   // 2M x 4N waves, 128x64 each
    const int lrow = lane & 15;
    const int lkb  = lane >> 4;                // k-octet 0..3

    // A-stage: 8 lanes/row (ak*4 floats), rows ar + 64p
    const int ar = tid >> 3;            // 0..63
    const int ak = tid & 7;
    // B-stage: wave gw owns k-quad gw; lane gc owns 4 cols
    const int gw = tid >> 6;            // 0..7
    const int gc = tid & 63;            // 0..63

    const size_t XS = (size_t)NL * DIN;
    const float* xb = x + (size_t)bm0 * XS + (size_t)layer * DIN;
    const float* wb = w + (size_t)layer * DIN * DOUT + bn0;
    const float* aptr0 = xb + (size_t)ar * XS + ak * 4;
    const float* bptr0 = wb + (size_t)(gw * 4) * DOUT + gc * 4;

    f32x4 acc[8][4];
#pragma unroll
    for (int i = 0; i < 8; ++i)
#pragma unroll
        for (int j = 0; j < 4; ++j) acc[i][j] = (f32x4){0.f, 0.f, 0.f, 0.f};

    f32x4 avE[4], avO[4];   // A ping-pong flight sets (2 intervals deep)
    f32x4 bv[4];            // B flight (1 interval)

    auto issueA = [&](int kt, f32x4 (&s)[4]) {
#pragma unroll
        for (int p = 0; p < 4; ++p)
            s[p] = *reinterpret_cast<const f32x4*>(
                aptr0 + (size_t)(64 * p) * XS + kt * BK);
    };
    auto issueB = [&](int kt) {
#pragma unroll
        for (int p = 0; p < 4; ++p)
            bv[p] = *reinterpret_cast<const f32x4*>(
                bptr0 + (size_t)(kt * BK + p) * DOUT);
    };

    auto cvtwriteA = [&](int db, f32x4 (&s)[4]) {
#pragma unroll
        for (int p = 0; p < 4; ++p) {
            uint2 wv;
            wv.x = pk2(s[p][0], s[p][1]);
            wv.y = pk2(s[p][2], s[p][3]);
            *reinterpret_cast<uint2*>(
                &As[db][(ar + 64 * p) * LDSS + ak * 4]) = wv;
        }
    };
    auto cvtwriteB = [&](int db) {
#pragma unroll
        for (int j = 0; j < 4; ++j) {
            const int c = gc * 4 + j;
            uint2 wv;
            wv.x = pk2(bv[0][j], bv[1][j]);
            wv.y = pk2(bv[2][j], bv[3][j]);
            const int slot = gw ^ ((c >> 2) & 7);        // bank-spread slot
            *reinterpret_cast<uint2*>(
                &Bs[db][c * LDSS + slot * 4]) = wv;
        }
    };

    auto fragA = [&](int db, short8* af) {
#pragma unroll
        for (int mi = 0; mi < 8; ++mi) {
            const int row = wr * 128 + mi * 16 + lrow;
            af[mi] = *reinterpret_cast<const short8*>(
                &As[db][row * LDSS + lkb * 8]);
        }
    };
    auto fragB = [&](int db, short8* bf) {
#pragma unroll
        for (int ni = 0; ni < 4; ++ni) {
            const int col = wc * 64 + ni * 16 + lrow;
            const int key = (col >> 2) & 7;
            const unsigned short* base = &Bs[db][col * LDSS];
            uint2 lo = *reinterpret_cast<const uint2*>(
                base + (((2 * lkb) ^ key) << 2));
            uint2 hi = *reinterpret_cast<const uint2*>(
                base + (((2 * lkb + 1) ^ key) << 2));
            uint4 u = make_uint4(lo.x, lo.y, hi.x, hi.y);
            __builtin_memcpy(&bf[ni], &u, 16);
        }
    };

#define BARRIER() do { \
        asm volatile("s_waitcnt lgkmcnt(0)" ::: "memory"); \
        __builtin_amdgcn_sched_barrier(0); \
        __builtin_amdgcn_s_barrier(); \
        __builtin_amdgcn_sched_barrier(0); } while (0)

#define MFMA32(AF, BF) do { \
        __builtin_amdgcn_s_setprio(1); \
        _Pragma("unroll") \
        for (int mi = 0; mi < 8; ++mi) \
        _Pragma("unroll") \
            for (int ni = 0; ni < 4; ++ni) \
                acc[mi][ni] = __builtin_amdgcn_mfma_f32_16x16x32_bf16( \
                    AF[mi], BF[ni], acc[mi][ni], 0, 0, 0); \
        __builtin_amdgcn_s_setprio(0); } while (0)

    // ---- prologue ----
    issueA(0, avE);         // tile0 -> E
    issueB(0);
    cvtwriteA(0, avE);      // stalls on A(0) HBM once
    cvtwriteB(0);
    issueA(1, avO);         // tile1 -> O
    issueB(1);
    issueA(2, avE);         // tile2 -> E (2 intervals ahead)
    BARRIER();

    // ---- steady state: 2-step unrolled (compile-time reg-set selection) ----
#pragma unroll 1
    for (int k = 0; k < NK - 2; k += 2) {
        {   // step A: tile k (even), buf0; stage k+1 from avO
            short8 af[8], bf[4];
            fragA(0, af);
            fragB(0, bf);
            cvtwriteA(1, avO);
            cvtwriteB(1);
            issueA(k + 3, avO);          // k<=12 -> k+3<=15, always valid
            issueB(k + 2);
            MFMA32(af, bf);
            BARRIER();
        }
        {   // step B: tile k+1 (odd), buf1; stage k+2 from avE
            short8 af[8], bf[4];
            fragA(1, af);
            fragB(1, bf);
            cvtwriteA(0, avE);
            cvtwriteB(0);
            if (k + 4 < NK) issueA(k + 4, avE);
            issueB(k + 3);
            MFMA32(af, bf);
            BARRIER();
        }
    }
    // ---- k = NK-2 (even, buf0): stage last tile (NK-1) from avO ----
    {
        short8 af[8], bf[4];
        fragA(0, af);
        fragB(0, bf);
        cvtwriteA(1, avO);
        cvtwriteB(1);
        MFMA32(af, bf);
        BARRIER();
    }
    // ---- k = NK-1 (odd, buf1): compute only ----
    {
        short8 af[8], bf[4];
        fragA(1, af);
        fragB(1, bf);
        MFMA32(af, bf);
    }

    // ---- epilogue: + bias, fp32 store ----
    const float* bb = bias + (size_t)layer * DOUT + bn0;
    float* ob = out + (size_t)bm0 * (NL * DOUT) + (size_t)layer * DOUT + bn0;
#pragma unroll
    for (int mi = 0; mi < 8; ++mi) {
#pragma unroll
        for (int ni = 0; ni < 4; ++ni) {
            const int col = wc * 64 + ni * 16 + lrow;
            const float bval = bb[col];
#pragma unroll
            for (int r = 0; r < 4; ++r) {
                const int row = wr * 128 + mi * 16 + lkb * 4 + r;
                ob[(size_t)row * (NL * DOUT) + col] = acc[mi][ni][r] + bval;
            }
        }
    }
#undef BARRIER
#undef MFMA32
}

extern "C" void kernel_launch(void* const* d_in, const int* in_sizes, int n_in,
                              void* d_out, int out_size, void* d_ws, size_t ws_size,
                              hipStream_t stream) {
    const float* x  = (const float*)d_in[0];
    const float* w  = (const float*)d_in[1];
    const float* b  = (const float*)d_in[2];
    float* out      = (float*)d_out;

    dim3 grid(NL * (BATCH / BM) * (DOUT / BN));   // 64 * 4 * 2 = 512
    dim3 block(512);
    hipLaunchKernelGGL(nlinear_kernel, grid, block, 0, stream, x, w, b, out);
}